// Round 8
// baseline (418.909 us; speedup 1.0000x reference)
//
#include <hip/hip_runtime.h>

// Trilinear 3D warp: image [1,1,256,256,256] f32, dvf [1,3,256,256,256] f32
// dvf channels: 0=dy, 1=dx, 2=dz. Layout (H,W,D), D innermost.
//
// R1: fused z-pair gather into one float2 load.
// R2: wave-level 3D tiling (wave = 16z x 4x).
// R3: bz-fastest schedule + XCD chunking + NT dvf loads + plain store: 150us.
// R4/R5: LDS staging -> regressed (208/186us). Abandoned.
// R6: 4-slot ILP -> 159us. MLP is not the limiter (TA request-service bound).
// R7: block 512 (8y x 4x x 16z): 141us. Occupancy/dispatch still paid ->
//     not yet flat against the request floor (~109us by line-request count).
// R8 (this): persistent z-column blocks. Each block owns one xy-tile and
//   loops bz = 0..15 in-block (8y x 4x x 256z per block). The jittered
//   z-halo lines shared by z-adjacent tiles now stay in the SAME CU's L1
//   across loop iterations (was: different block, usually different CU,
//   caught only by L2). Grid 32768 -> 2048 blocks (= the 32x64 xy-tile
//   count) cuts residual dispatch overhead. Per-iteration access pattern
//   is byte-identical to R7. XCD chunking keeps x-halo sharers (distance
//   1 block) on the same XCD L2.

constexpr int H = 256, W = 256, D = 256;
constexpr int N = H * W * D;
constexpr int NXY = 2048;           // 64 x-tiles * 32 y-tiles

__global__ __launch_bounds__(512) void warp3d_kernel(
    const float* __restrict__ img,
    const float* __restrict__ dvf,
    float* __restrict__ out)
{
    // lane -> (z,x), wave -> y (identical wave shape to R3/R7)
    const int t  = threadIdx.x;
    const int zt = t & 15;          // 16 z per wave
    const int xt = (t >> 4) & 3;    // 4 x per wave
    const int yt = t >> 6;          // wave id = y within tile (0..7)

    // XCD-contiguous remap (2048 % 8 == 0, bijective); bx fastest so
    // x-halo-sharing neighbors are adjacent on the same XCD's L2.
    const int orig    = blockIdx.x;
    const int logical = (orig & 7) * (NXY / 8) + (orig >> 3);
    const int bx = logical & 63;          // 64 x-tiles (fastest)
    const int by = logical >> 6;          // 32 y-tiles

    const int x = (bx << 2) + xt;
    const int y = (by << 3) + yt;
    const int ibase = (y << 16) | (x << 8);

    // persistent loop over the z-column: z-halo lines stay in this CU's L1
    for (int bz = 0; bz < 16; ++bz) {
        const int z = (bz << 4) + zt;
        const int i = ibase | z;

        // dvf stream loads: single-touch, keep out of cache
        const float dy = __builtin_nontemporal_load(dvf + i);
        const float dx = __builtin_nontemporal_load(dvf + i + N);
        const float dz = __builtin_nontemporal_load(dvf + i + 2 * N);

        const float ny = (float)y + dy;
        const float nx = (float)x + dx;
        const float nz = (float)z + dz;

        const int iy = (int)floorf(ny);
        const int ix = (int)floorf(nx);
        const int iz = (int)floorf(nz);

        const int y0 = min(max(iy,     0), H - 1);
        const int y1 = min(max(iy + 1, 0), H - 1);
        const int x0 = min(max(ix,     0), W - 1);
        const int x1 = min(max(ix + 1, 0), W - 1);
        const int z0 = min(max(iz,     0), D - 1);
        const int z1 = min(max(iz + 1, 0), D - 1);

        // fractions use the CLIPPED low corner (matches reference exactly)
        const float yd = ny - (float)y0;
        const float xd = nx - (float)x0;
        const float zd = nz - (float)z0;

        const int zb = min(z0, D - 2);
        const bool lo = (z0 == zb);       // low corner is v.x
        const bool hi = (z1 == zb + 1);   // high corner is v.y

        const int r00 = (((y0 << 8) + x0) << 8) + zb;
        const int r01 = (((y0 << 8) + x1) << 8) + zb;
        const int r10 = (((y1 << 8) + x0) << 8) + zb;
        const int r11 = (((y1 << 8) + x1) << 8) + zb;

        // one 8B gather per corner column (4B-aligned; HW handles split)
        const float2 v00 = *reinterpret_cast<const float2*>(img + r00);
        const float2 v01 = *reinterpret_cast<const float2*>(img + r01);
        const float2 v10 = *reinterpret_cast<const float2*>(img + r10);
        const float2 v11 = *reinterpret_cast<const float2*>(img + r11);

        const float c000 = lo ? v00.x : v00.y;
        const float c001 = hi ? v00.y : v00.x;
        const float c010 = lo ? v01.x : v01.y;
        const float c011 = hi ? v01.y : v01.x;
        const float c100 = lo ? v10.x : v10.y;
        const float c101 = hi ? v10.y : v10.x;
        const float c110 = lo ? v11.x : v11.y;
        const float c111 = hi ? v11.y : v11.x;

        const float omz = 1.0f - zd;
        const float c00 = c000 * omz + c001 * zd;
        const float c01 = c010 * omz + c011 * zd;
        const float c10 = c100 * omz + c101 * zd;
        const float c11 = c110 * omz + c111 * zd;

        const float omx = 1.0f - xd;
        const float c0 = c00 * omx + c01 * xd;
        const float c1 = c10 * omx + c11 * xd;

        out[i] = c0 * (1.0f - yd) + c1 * yd;   // plain store: L2 coalesces
    }
}

extern "C" void kernel_launch(void* const* d_in, const int* in_sizes, int n_in,
                              void* d_out, int out_size, void* d_ws, size_t ws_size,
                              hipStream_t stream) {
    const float* img = (const float*)d_in[0];
    const float* dvf = (const float*)d_in[1];
    float* out = (float*)d_out;

    dim3 block(512);
    dim3 grid(NXY);   // 2048 persistent z-column blocks (8y x 4x x 256z)
    warp3d_kernel<<<grid, block, 0, stream>>>(img, dvf, out);
}

// Round 9
// 387.351 us; speedup vs baseline: 1.0815x; 1.0815x over previous
//
#include <hip/hip_runtime.h>

// Trilinear 3D warp: image [1,1,256,256,256] f32, dvf [1,3,256,256,256] f32
// dvf channels: 0=dy, 1=dx, 2=dz. Layout (H,W,D), D innermost.
//
// FINAL (R9 = revert to R7, the measured best at 141us/dispatch):
// R1: fused z-pair gather into one float2 load.
// R2: wave-level 3D tiling (wave = 16z x 4x).
// R3: bz-fastest schedule + XCD chunking + NT dvf loads + plain store: 150us.
// R4/R5: LDS staging -> regressed (208/186us). Staging amplification +
//   stage->sync->gather serialization loses to direct gather via L1.
// R6: 4-slot ILP -> 159us. MLP is not the limiter.
// R7: block 512 (8y x 4x x 16z): 141us. BEST.
// R8: persistent z-column blocks -> 171us, FETCH +82MB. The bz-fastest
//   DISPATCH order was doing the cache-blocking; in-block z-loops with
//   async drift spread the working set and lose it. Reverted.
//
// Counter signature at 141us: HBM 17%, VALU 25%, occupancy 75%, LDS 0,
// bank-conflict 0 -> TA/L1 request-service bound. Request count per output
// is irreducible for a gather formulation (4 corners on provably distinct
// lines; z-pair fused; dvf/store lines minimal). Practical roofline.

constexpr int H = 256, W = 256, D = 256;
constexpr int N = H * W * D;
constexpr int NBLK = N / 512;       // 32768 tiles of 8y x 4x x 16z

__global__ __launch_bounds__(512) void warp3d_kernel(
    const float* __restrict__ img,
    const float* __restrict__ dvf,
    float* __restrict__ out)
{
    // lane -> (z,x), wave -> y
    const int t  = threadIdx.x;
    const int zt = t & 15;          // 16 z per wave
    const int xt = (t >> 4) & 3;    // 4 x per wave
    const int yt = t >> 6;          // wave id = y within tile (0..7)

    // XCD-contiguous remap (32768 % 8 == 0, bijective), bz fastest
    const int orig    = blockIdx.x;
    const int logical = (orig & 7) * (NBLK / 8) + (orig >> 3);
    const int bz = logical & 15;          // 16 z-tiles   (fastest)
    const int bx = (logical >> 4) & 63;   // 64 x-tiles
    const int by = logical >> 10;         // 32 y-tiles   (slowest)

    const int z = (bz << 4) + zt;
    const int x = (bx << 2) + xt;
    const int y = (by << 3) + yt;

    const int i = (y << 16) | (x << 8) | z;   // (y*W + x)*D + z, dims all 256

    // dvf stream loads: single-touch, keep out of cache
    const float dy = __builtin_nontemporal_load(dvf + i);
    const float dx = __builtin_nontemporal_load(dvf + i + N);
    const float dz = __builtin_nontemporal_load(dvf + i + 2 * N);

    const float ny = (float)y + dy;
    const float nx = (float)x + dx;
    const float nz = (float)z + dz;

    const int iy = (int)floorf(ny);
    const int ix = (int)floorf(nx);
    const int iz = (int)floorf(nz);

    const int y0 = min(max(iy,     0), H - 1);
    const int y1 = min(max(iy + 1, 0), H - 1);
    const int x0 = min(max(ix,     0), W - 1);
    const int x1 = min(max(ix + 1, 0), W - 1);
    const int z0 = min(max(iz,     0), D - 1);
    const int z1 = min(max(iz + 1, 0), D - 1);

    // fractions use the CLIPPED low corner (matches reference exactly)
    const float yd = ny - (float)y0;
    const float xd = nx - (float)x0;
    const float zd = nz - (float)z0;

    const int zb = min(z0, D - 2);
    const bool lo = (z0 == zb);       // low corner is v.x
    const bool hi = (z1 == zb + 1);   // high corner is v.y

    const int r00 = (y0 * W + x0) * D + zb;
    const int r01 = (y0 * W + x1) * D + zb;
    const int r10 = (y1 * W + x0) * D + zb;
    const int r11 = (y1 * W + x1) * D + zb;

    // one 8B gather per corner column (4B-aligned; gfx950 handles unaligned)
    const float2 v00 = *reinterpret_cast<const float2*>(img + r00);
    const float2 v01 = *reinterpret_cast<const float2*>(img + r01);
    const float2 v10 = *reinterpret_cast<const float2*>(img + r10);
    const float2 v11 = *reinterpret_cast<const float2*>(img + r11);

    const float c000 = lo ? v00.x : v00.y;
    const float c001 = hi ? v00.y : v00.x;
    const float c010 = lo ? v01.x : v01.y;
    const float c011 = hi ? v01.y : v01.x;
    const float c100 = lo ? v10.x : v10.y;
    const float c101 = hi ? v10.y : v10.x;
    const float c110 = lo ? v11.x : v11.y;
    const float c111 = hi ? v11.y : v11.x;

    const float omz = 1.0f - zd;
    const float c00 = c000 * omz + c001 * zd;
    const float c01 = c010 * omz + c011 * zd;
    const float c10 = c100 * omz + c101 * zd;
    const float c11 = c110 * omz + c111 * zd;

    const float omx = 1.0f - xd;
    const float c0 = c00 * omx + c01 * xd;
    const float c1 = c10 * omx + c11 * xd;

    out[i] = c0 * (1.0f - yd) + c1 * yd;   // plain store: L2 coalesces lines
}

extern "C" void kernel_launch(void* const* d_in, const int* in_sizes, int n_in,
                              void* d_out, int out_size, void* d_ws, size_t ws_size,
                              hipStream_t stream) {
    const float* img = (const float*)d_in[0];
    const float* dvf = (const float*)d_in[1];
    float* out = (float*)d_out;

    dim3 block(512);
    dim3 grid(NBLK);   // 32768 tiles of 8y x 4x x 16z
    warp3d_kernel<<<grid, block, 0, stream>>>(img, dvf, out);
}